// Round 1
// 69.338 us; speedup vs baseline: 1.0292x; 1.0292x over previous
//
#include <hip/hip_runtime.h>

// exp[n,h] = sum_{i<48,j<48} obs_re[h,i,j] * x[n,i] * x[n,j]
// (psi real => Im part cancels; obs_im unused; padding i,j>=48 zero)
//
// Two kernels:
//  1) prep_frags: obs_re -> bf16 MFMA A-fragments in d_ws (48 KB), once per call.
//     Removes the per-block div/mod + f2bf conversion that 512 blocks redundantly did.
//  2) qform_main: per block stage frags ws->LDS (coalesced copy) + 128-token x tile;
//     waves head-split (4 heads x 64 tokens each) to halve per-wave A LDS reads.

#define NTOK 65536
#define NHEAD 8
#define XSTRIDE 56           // shorts per LDS x-row (48 data + 8 pad) = 112 B
#define TPB 128              // tokens per block

typedef __attribute__((ext_vector_type(8))) short short8;
typedef __attribute__((ext_vector_type(4))) short short4v;
typedef __attribute__((ext_vector_type(4))) float float4v;

static __device__ __forceinline__ short f2bf(float f) {
    unsigned int u = __builtin_bit_cast(unsigned int, f);
    u += 0x7FFFu + ((u >> 16) & 1u);        // round-to-nearest-even
    return (short)(u >> 16);
}
static __device__ __forceinline__ float bf2f(short s) {
    return __builtin_bit_cast(float, ((unsigned int)(unsigned short)s) << 16);
}

// ---------------------------------------------------------------------------
// Prep: frag f = h*6 + kt*3 + it; lane (q,c), lane = 16q+c, holds
// frags[(f*64+lane)*8 + jj] = bf16(obs[h][16*it + c][32*kt + 8*q + jj])
// (identical mapping to the previously-validated in-kernel staging)
// ---------------------------------------------------------------------------
__global__ void prep_frags(const float* __restrict__ obs, short* __restrict__ frags) {
    const int tid  = threadIdx.x;
    const int w    = tid >> 6, lane = tid & 63;
    const int q    = lane >> 4, c = lane & 15;
    const int h    = blockIdx.x * 4 + w;        // 2 blocks x 4 waves -> heads 0..7
    #pragma unroll
    for (int u = 0; u < 6; ++u) {               // kt,it compile-time after unroll
        const int kt = u / 3, it = u % 3;
        const int f  = h * 6 + u;
        const float4* src = (const float4*)(obs +
            ((size_t)(h * 64 + 16 * it + c) * 64 + 32 * kt + 8 * q));
        float4 v0 = src[0], v1 = src[1];
        short8 a;
        a[0] = f2bf(v0.x); a[1] = f2bf(v0.y); a[2] = f2bf(v0.z); a[3] = f2bf(v0.w);
        a[4] = f2bf(v1.x); a[5] = f2bf(v1.y); a[6] = f2bf(v1.z); a[7] = f2bf(v1.w);
        *(short8*)(frags + ((size_t)f * 64 + lane) * 8) = a;
    }
}

// ---------------------------------------------------------------------------
// Main: 256 threads, 128 tokens/block.
// Wave roles: hbase = (w>>1)*4 (heads 0-3 or 4-7), gbase = (w&1)*4 (tokens 0-63 or 64-127).
// Each wave: 4 heads x 4 token-groups of 16 via mfma_f32_16x16x32_bf16.
// ---------------------------------------------------------------------------
__global__ __launch_bounds__(256, 2) void qform_main(
    const short* __restrict__ frags,    // (48, 64, 8) bf16 A-frags in d_ws
    const float* __restrict__ x,        // (65536, 48)
    float* __restrict__ out)            // (65536, 8)
{
    __shared__ short a_lds[48 * 64 * 8];        // 48 KB
    __shared__ short xl[TPB * XSTRIDE];         // 14 KB

    const int tid  = threadIdx.x;
    const int w    = tid >> 6, lane = tid & 63;
    const int q    = lane >> 4, c = lane & 15;
    const int tb   = blockIdx.x * TPB;

    // ---- stage A-frags: straight coalesced copy ws -> LDS (1 KB per instr/wave) ----
    #pragma unroll
    for (int u = 0; u < 12; ++u) {
        const int f = u * 4 + w;                // wave w copies frags w, w+4, ...
        short8 a = *(const short8*)(frags + ((size_t)f * 64 + lane) * 8);
        *(short8*)(a_lds + ((size_t)f * 64 + lane) * 8) = a;
    }

    // ---- stage x tile: 128 tokens x 12 float4, coalesced ----
    #pragma unroll
    for (int s = 0; s < 6; ++s) {
        int idx = s * 256 + tid;                // 0..1535
        int t = idx / 12, ch = idx % 12;
        float4 v = ((const float4*)x)[(size_t)tb * 12 + idx];
        short4v b;
        b.x = f2bf(v.x); b.y = f2bf(v.y); b.z = f2bf(v.z); b.w = f2bf(v.w);
        *(short4v*)(xl + t * XSTRIDE + ch * 4) = b;
    }
    __syncthreads();

    const int hbase = (w >> 1) * 4;
    const int gbase = (w & 1) * 4;

    // ---- per-wave B-fragments + epilogue x values for 4 groups of 16 tokens ----
    short8 bfr[4][2];
    float  xe[4][3][4];
    #pragma unroll
    for (int g = 0; g < 4; ++g) {
        const int row = (gbase + g) * 16 + c;   // token within block
        bfr[g][0] = *(const short8*)(xl + row * XSTRIDE + q * 8);
        if (q < 2)
            bfr[g][1] = *(const short8*)(xl + row * XSTRIDE + 32 + q * 8);
        else
            bfr[g][1] = (short8)0;              // j >= 48: psi-pad is zero
        #pragma unroll
        for (int it = 0; it < 3; ++it)
            #pragma unroll
            for (int r = 0; r < 4; ++r)
                xe[g][it][r] = bf2f(xl[row * XSTRIDE + 16 * it + 4 * q + r]);
    }

    float ph[4][4];                             // [group][head-within-half]
    #pragma unroll
    for (int hh = 0; hh < 4; ++hh) {
        const int h = hbase + hh;
        short8 A[6];
        #pragma unroll
        for (int u = 0; u < 6; ++u)
            A[u] = *(const short8*)(a_lds + ((size_t)(h * 6 + u) * 64 + lane) * 8);
        #pragma unroll
        for (int g = 0; g < 4; ++g) {
            float4v acc[3];
            #pragma unroll
            for (int it = 0; it < 3; ++it) {
                float4v z = {0.f, 0.f, 0.f, 0.f};
                acc[it] = __builtin_amdgcn_mfma_f32_16x16x32_bf16(A[it],     bfr[g][0], z,       0, 0, 0);
                acc[it] = __builtin_amdgcn_mfma_f32_16x16x32_bf16(A[3 + it], bfr[g][1], acc[it], 0, 0, 0);
            }
            float p = 0.f;
            #pragma unroll
            for (int it = 0; it < 3; ++it)
                #pragma unroll
                for (int r = 0; r < 4; ++r)
                    p += acc[it][r] * xe[g][it][r];   // x[row][16it+4q+r] * D[i][row]
            p += __shfl_xor(p, 16, 64);               // reduce over q
            p += __shfl_xor(p, 32, 64);
            ph[g][hh] = p;
        }
    }

    // ---- store: lanes 0..15 write one float4 (4 heads) per group ----
    if (lane < 16) {
        #pragma unroll
        for (int g = 0; g < 4; ++g) {
            float4* o4 = (float4*)(out +
                (size_t)(tb + (gbase + g) * 16 + c) * NHEAD + hbase);
            o4[0] = make_float4(ph[g][0], ph[g][1], ph[g][2], ph[g][3]);
        }
    }
}

extern "C" void kernel_launch(void* const* d_in, const int* in_sizes, int n_in,
                              void* d_out, int out_size, void* d_ws, size_t ws_size,
                              hipStream_t stream) {
    const float* x      = (const float*)d_in[0];   // (16,4096,48)
    const float* obs_re = (const float*)d_in[1];   // (8,64,64)
    // d_in[2] = obs_im: unused (Re(psi^H O psi) with real psi)
    float* out   = (float*)d_out;                  // (16,4096,8)
    short* frags = (short*)d_ws;                   // 48 KB of bf16 A-fragments

    prep_frags<<<2, 256, 0, stream>>>(obs_re, frags);
    qform_main<<<NTOK / TPB, 256, 0, stream>>>(frags, x, out);
}

// Round 2
// 68.663 us; speedup vs baseline: 1.0393x; 1.0098x over previous
//
#include <hip/hip_runtime.h>

// exp[n,h] = sum_{i<48,j<48} obs_re[h,i,j] * x[n,i] * x[n,j]
// (psi real => Im part cancels; obs_im unused; padding i,j>=48 zero)
//
// Single fused kernel, 512 threads (8 waves), 256 tokens/block, 256 blocks
// (1 per CU). Wave w stages head w's 6 MFMA A-fragments (all indices
// compile-time after unroll -> no div/mod). x loads issued before obs
// conversion so HBM latency hides under f2bf VALU work. Epilogue x values
// via ds_read_b64 (4x fewer LDS instrs than scalar u16 reads).

#define NTOK 65536
#define NHEAD 8
#define XSTRIDE 56           // shorts per LDS x-row (48 data + 8 pad) = 112 B
#define TPB 256              // tokens per block
#define NTHREADS 512

typedef __attribute__((ext_vector_type(8))) short short8;
typedef __attribute__((ext_vector_type(4))) short short4v;
typedef __attribute__((ext_vector_type(4))) float float4v;

static __device__ __forceinline__ short f2bf(float f) {
    unsigned int u = __builtin_bit_cast(unsigned int, f);
    u += 0x7FFFu + ((u >> 16) & 1u);        // round-to-nearest-even
    return (short)(u >> 16);
}
static __device__ __forceinline__ float bf2f(short s) {
    return __builtin_bit_cast(float, ((unsigned int)(unsigned short)s) << 16);
}

__global__ __launch_bounds__(NTHREADS, 2) void qform_fused(
    const float* __restrict__ x,        // (65536, 48)
    const float* __restrict__ obs,      // (8, 64, 64)
    float* __restrict__ out)            // (65536, 8)
{
    __shared__ short a_lds[48 * 64 * 8];        // 48 KB
    __shared__ short xl[TPB * XSTRIDE];         // 28 KB

    const int tid  = threadIdx.x;
    const int w    = tid >> 6, lane = tid & 63;
    const int q    = lane >> 4, c = lane & 15;
    const int tb   = blockIdx.x * TPB;

    // ---- issue x tile loads FIRST (latency hides under obs conversion) ----
    float4 xv[6];
    int    xt[6], xch[6];
    #pragma unroll
    for (int s = 0; s < 6; ++s) {
        int idx = s * NTHREADS + tid;           // 0..3071
        xv[s]  = ((const float4*)x)[(size_t)tb * 12 + idx];
        xt[s]  = idx / 12;
        xch[s] = idx % 12;
    }

    // ---- stage A-frags: wave w converts head w's 6 frags (f = w*6 + u).
    // frag f = h*6 + kt*3 + it; lane (q,c) holds
    // A[m=c][k=8q+jj] = obs[h][16it+c][32kt+8q+jj]  (validated mapping) ----
    #pragma unroll
    for (int u = 0; u < 6; ++u) {
        const int kt = u / 3, it = u % 3;       // compile-time after unroll
        const float4* src = (const float4*)(obs +
            ((size_t)(w * 64 + 16 * it + c) * 64 + 32 * kt + 8 * q));
        float4 v0 = src[0], v1 = src[1];
        short8 a;
        a[0] = f2bf(v0.x); a[1] = f2bf(v0.y); a[2] = f2bf(v0.z); a[3] = f2bf(v0.w);
        a[4] = f2bf(v1.x); a[5] = f2bf(v1.y); a[6] = f2bf(v1.z); a[7] = f2bf(v1.w);
        *(short8*)(a_lds + ((size_t)(w * 6 + u) * 64 + lane) * 8) = a;
    }

    // ---- convert + store x tile (loads issued above have landed by now) ----
    #pragma unroll
    for (int s = 0; s < 6; ++s) {
        short4v b;
        b.x = f2bf(xv[s].x); b.y = f2bf(xv[s].y);
        b.z = f2bf(xv[s].z); b.w = f2bf(xv[s].w);
        *(short4v*)(xl + xt[s] * XSTRIDE + xch[s] * 4) = b;
    }
    __syncthreads();

    // ---- wave roles: 2-way head split x 4-way token split ----
    const int hbase = (w >> 2) * 4;             // heads 0-3 or 4-7
    const int gbase = (w & 3) * 4;              // token-groups of 16

    // ---- per-wave B-fragments + epilogue x values for 4 groups ----
    short8 bfr[4][2];
    float  xe[4][3][4];
    #pragma unroll
    for (int g = 0; g < 4; ++g) {
        const int row = (gbase + g) * 16 + c;   // token within block
        bfr[g][0] = *(const short8*)(xl + row * XSTRIDE + q * 8);
        if (q < 2)
            bfr[g][1] = *(const short8*)(xl + row * XSTRIDE + 32 + q * 8);
        else
            bfr[g][1] = (short8)0;              // j >= 48: psi-pad is zero
        #pragma unroll
        for (int it = 0; it < 3; ++it) {
            short4v xs = *(const short4v*)(xl + row * XSTRIDE + 16 * it + 4 * q);
            xe[g][it][0] = bf2f(xs.x); xe[g][it][1] = bf2f(xs.y);
            xe[g][it][2] = bf2f(xs.z); xe[g][it][3] = bf2f(xs.w);
        }
    }

    float ph[4][4];                             // [group][head-within-half]
    #pragma unroll
    for (int hh = 0; hh < 4; ++hh) {
        const int h = hbase + hh;
        short8 A[6];
        #pragma unroll
        for (int u = 0; u < 6; ++u)
            A[u] = *(const short8*)(a_lds + ((size_t)(h * 6 + u) * 64 + lane) * 8);
        #pragma unroll
        for (int g = 0; g < 4; ++g) {
            float4v acc[3];
            #pragma unroll
            for (int it = 0; it < 3; ++it) {
                float4v z = {0.f, 0.f, 0.f, 0.f};
                acc[it] = __builtin_amdgcn_mfma_f32_16x16x32_bf16(A[it],     bfr[g][0], z,       0, 0, 0);
                acc[it] = __builtin_amdgcn_mfma_f32_16x16x32_bf16(A[3 + it], bfr[g][1], acc[it], 0, 0, 0);
            }
            float p = 0.f;
            #pragma unroll
            for (int it = 0; it < 3; ++it)
                #pragma unroll
                for (int r = 0; r < 4; ++r)
                    p += acc[it][r] * xe[g][it][r];   // x[row][16it+4q+r] * D[i][row]
            p += __shfl_xor(p, 16, 64);               // reduce over q
            p += __shfl_xor(p, 32, 64);
            ph[g][hh] = p;
        }
    }

    // ---- store: lanes 0..15 write one float4 (4 heads) per group ----
    if (lane < 16) {
        #pragma unroll
        for (int g = 0; g < 4; ++g) {
            float4* o4 = (float4*)(out +
                (size_t)(tb + (gbase + g) * 16 + c) * NHEAD + hbase);
            o4[0] = make_float4(ph[g][0], ph[g][1], ph[g][2], ph[g][3]);
        }
    }
}

extern "C" void kernel_launch(void* const* d_in, const int* in_sizes, int n_in,
                              void* d_out, int out_size, void* d_ws, size_t ws_size,
                              hipStream_t stream) {
    const float* x      = (const float*)d_in[0];   // (16,4096,48)
    const float* obs_re = (const float*)d_in[1];   // (8,64,64)
    // d_in[2] = obs_im: unused (Re(psi^H O psi) with real psi)
    float* out = (float*)d_out;                    // (16,4096,8)

    qform_fused<<<NTOK / TPB, NTHREADS, 0, stream>>>(x, obs_re, out);
}